// Round 13
// baseline (32.044 us; speedup 1.0000x reference)
//
#include <hip/hip_runtime.h>
#include <hip/hip_bf16.h>
#include <cstdint>
#include <cstddef>

// Problem constants
#define Bsz 16384
#define Esz 16
#define Ssz 64
#define Asz 32
#define Isz 96   // S + A
#define HSz 64
#define HRz 32

#define PT 512        // prep threads
#define NTM 256       // 4 waves
#define CHUNK 512     // batch rows per block
#define NTILE 8       // CHUNK / (4 waves * 16 rows)
#define WELEMS 13312  // per-e fragment elems: W1 6144 | rW1 3072 | W2 4096

typedef __attribute__((ext_vector_type(8))) short bf16x8;
typedef __attribute__((ext_vector_type(4))) short short4v;
typedef __attribute__((ext_vector_type(4))) float f32x4;

static __device__ __forceinline__ short f2bf(float f) {
    __hip_bfloat16 b = __float2bfloat16(f);   // pairs into v_cvt_pk_bf16_f32
    return *reinterpret_cast<short*>(&b);
}
static __device__ __forceinline__ float bf2f(short s) {
    union { uint32_t u; float f; } v; v.u = ((uint32_t)(uint16_t)s) << 16; return v.f;
}
static __device__ __forceinline__ bf16x8 pack8(float4 lo, float4 hi) {
    bf16x8 r;
    r[0] = f2bf(lo.x); r[1] = f2bf(lo.y); r[2] = f2bf(lo.z); r[3] = f2bf(lo.w);
    r[4] = f2bf(hi.x); r[5] = f2bf(hi.y); r[6] = f2bf(hi.z); r[7] = f2bf(hi.w);
    return r;
}

// ---- Prep: weights -> bf16 MFMA fragment order (proven R4/R9 layout) ----
// Wf[e*WELEMS + r]: [0,6144) W1 [nt4][kk3][lane][8]; [6144,9216) rW1 [nt2][kk3][lane][8];
// [9216,13312) W2 [nt4][kk2][lane][8].
// Fragment: lane l holds W[k = kk*32 + (l>>4)*8 + t][n = nt*16 + (l&15)], t=0..7
__global__ void prep_w(const float* __restrict__ W1, const float* __restrict__ rW1,
                       const float* __restrict__ W2, short* __restrict__ Wf) {
    int idx = blockIdx.x * blockDim.x + threadIdx.x;   // [0, Esz*WELEMS)
    int e = idx / WELEMS, r = idx - e * WELEMS;
    float v;
    if (r < 6144) {
        int nt = r / 1536, r2 = r % 1536, kk = r2 / 512, r3 = r2 % 512, l = r3 >> 3, t = r3 & 7;
        int i = kk * 32 + (l >> 4) * 8 + t, h = nt * 16 + (l & 15);
        v = W1[(size_t)e * Isz * HSz + i * HSz + h];
    } else if (r < 9216) {
        int r1 = r - 6144;
        int nt = r1 / 1536, r2 = r1 % 1536, kk = r2 / 512, r3 = r2 % 512, l = r3 >> 3, t = r3 & 7;
        int i = kk * 32 + (l >> 4) * 8 + t, h = nt * 16 + (l & 15);
        v = rW1[(size_t)e * Isz * HRz + i * HRz + h];
    } else {
        int r1 = r - 9216;
        int nt = r1 / 1024, r2 = r1 % 1024, kk = r2 / 512, r3 = r2 % 512, l = r3 >> 3, t = r3 & 7;
        int hk = kk * 32 + (l >> 4) * 8 + t, s = nt * 16 + (l & 15);
        v = W2[(size_t)e * HSz * Ssz + hk * Ssz + s];
    }
    Wf[idx] = f2bf(v);
}

// R12 winner + fragment-ordered weight loads (26 b128 loads replace 208 scalar).
// One ensemble per block; weights in VGPRs; swapped-operand MFMAs
// (D lane: m = lane&15, n = nt*16+(lane>>4)*4+j). XCD swizzle keeps the 16
// e-siblings of each batch chunk on one XCD; nt-stores keep the output stream
// from evicting X/weights out of L2.
__global__ __launch_bounds__(NTM, 2)
void fused_all(const float* __restrict__ state, const float* __restrict__ action,
               const short* __restrict__ Wf,
               const float* __restrict__ b1, const float* __restrict__ b2,
               const float* __restrict__ rb1, const float* __restrict__ rW2,
               const float* __restrict__ rb2,
               float* __restrict__ outS, float* __restrict__ outR)
{
    // Per-wave H buffer [m=16][h=64], row stride 68 shorts (136 B):
    // b64 writes / b128 reads both ~2-way max (free). 8704 B total.
    __shared__ __align__(16) short HT[4][16][68];

    // ---- XCD-aware sibling swizzle (bijective over 512 blocks) ----
    const int bid = blockIdx.x;
    const int xcd = bid & 7;
    const int rem = bid >> 3;
    const int e   = rem & (Esz - 1);
    const int c0  = (xcd + 8 * (rem >> 4)) * CHUNK;

    const int w = threadIdx.x >> 6, lane = threadIdx.x & 63;
    const int lr = lane & 15, lg = lane >> 4;

    // ---- Weight fragments: one b128 load each from fragment-ordered workspace ----
    bf16x8 w1r[4][3], rw1r[2][3], w2r[4][2];
    {
        const short* p = Wf + (size_t)e * WELEMS + lane * 8;
        #pragma unroll
        for (int nt = 0; nt < 4; ++nt)
            #pragma unroll
            for (int kk = 0; kk < 3; ++kk)
                w1r[nt][kk] = *(const bf16x8*)(p + (nt * 3 + kk) * 512);
        #pragma unroll
        for (int nt = 0; nt < 2; ++nt)
            #pragma unroll
            for (int kk = 0; kk < 3; ++kk)
                rw1r[nt][kk] = *(const bf16x8*)(p + 6144 + (nt * 3 + kk) * 512);
        #pragma unroll
        for (int nt = 0; nt < 4; ++nt)
            #pragma unroll
            for (int kk = 0; kk < 2; ++kk)
                w2r[nt][kk] = *(const bf16x8*)(p + 9216 + (nt * 2 + kk) * 512);
    }

    // ---- Biases packed bf16 (lane's D slots: n = nt*16 + lg*4 + j) ----
    short4v b1p[4], b2p[4], rb1p[2], rw2p[2];
    #pragma unroll
    for (int nt = 0; nt < 4; ++nt) {
        float4 v1 = *(const float4*)&b1[e * HSz + nt * 16 + lg * 4];
        float4 v2 = *(const float4*)&b2[e * Ssz + nt * 16 + lg * 4];
        b1p[nt] = (short4v){ f2bf(v1.x), f2bf(v1.y), f2bf(v1.z), f2bf(v1.w) };
        b2p[nt] = (short4v){ f2bf(v2.x), f2bf(v2.y), f2bf(v2.z), f2bf(v2.w) };
    }
    #pragma unroll
    for (int nt = 0; nt < 2; ++nt) {
        float4 v1 = *(const float4*)&rb1[e * HRz + nt * 16 + lg * 4];
        float4 v2 = *(const float4*)&rW2[e * HRz + nt * 16 + lg * 4];
        rb1p[nt] = (short4v){ f2bf(v1.x), f2bf(v1.y), f2bf(v1.z), f2bf(v1.w) };
        rw2p[nt] = (short4v){ f2bf(v2.x), f2bf(v2.y), f2bf(v2.z), f2bf(v2.w) };
    }
    const float rb2s = rb2[e];

    // ---- X pipeline: f32 loads (prefetched) -> cvt_pk -> bf16 fragments ----
    const int row0 = c0 + w * 16 + lr;               // this lane's base batch row (m = lr)
    const float* sbase = state  + (size_t)row0 * Ssz + lg * 8;
    const float* abase = action + (size_t)row0 * Asz + lg * 8;

    float4 xs0 = *(const float4*)(sbase);
    float4 xs1 = *(const float4*)(sbase + 4);
    float4 xs2 = *(const float4*)(sbase + 32);
    float4 xs3 = *(const float4*)(sbase + 36);
    float4 xa0 = *(const float4*)(abase);
    float4 xa1 = *(const float4*)(abase + 4);
    bf16x8 a0 = pack8(xs0, xs1);
    bf16x8 a1 = pack8(xs2, xs3);
    bf16x8 a2 = pack8(xa0, xa1);

    #pragma unroll 1
    for (int t = 0; t < NTILE; ++t) {
        // Prefetch next tile's f32 rows (wraps on last iter; L2-hit, discarded)
        const int tn = (t + 1) & (NTILE - 1);
        const float* sp = sbase + (size_t)tn * 64 * Ssz;
        const float* ap = abase + (size_t)tn * 64 * Asz;
        float4 ns0 = *(const float4*)(sp);
        float4 ns1 = *(const float4*)(sp + 4);
        float4 ns2 = *(const float4*)(sp + 32);
        float4 ns3 = *(const float4*)(sp + 36);
        float4 na0 = *(const float4*)(ap);
        float4 na1 = *(const float4*)(ap + 4);

        // ---- Layer 1 (state): acc initialized with bias (free add) ----
        f32x4 accS[4];
        #pragma unroll
        for (int nt = 0; nt < 4; ++nt) {
            f32x4 acc = (f32x4){ bf2f(b1p[nt][0]), bf2f(b1p[nt][1]),
                                 bf2f(b1p[nt][2]), bf2f(b1p[nt][3]) };
            acc = __builtin_amdgcn_mfma_f32_16x16x32_bf16(w1r[nt][0], a0, acc, 0, 0, 0);
            acc = __builtin_amdgcn_mfma_f32_16x16x32_bf16(w1r[nt][1], a1, acc, 0, 0, 0);
            acc = __builtin_amdgcn_mfma_f32_16x16x32_bf16(w1r[nt][2], a2, acc, 0, 0, 0);
            accS[nt] = acc;
        }
        // ---- Layer 1 (reward) ----
        f32x4 accR[2];
        #pragma unroll
        for (int nt = 0; nt < 2; ++nt) {
            f32x4 acc = (f32x4){ bf2f(rb1p[nt][0]), bf2f(rb1p[nt][1]),
                                 bf2f(rb1p[nt][2]), bf2f(rb1p[nt][3]) };
            acc = __builtin_amdgcn_mfma_f32_16x16x32_bf16(rw1r[nt][0], a0, acc, 0, 0, 0);
            acc = __builtin_amdgcn_mfma_f32_16x16x32_bf16(rw1r[nt][1], a1, acc, 0, 0, 0);
            acc = __builtin_amdgcn_mfma_f32_16x16x32_bf16(rw1r[nt][2], a2, acc, 0, 0, 0);
            accR[nt] = acc;
        }

        // ---- H = relu(accS) -> HT (lane holds 4 consecutive h of row lr) ----
        #pragma unroll
        for (int nt = 0; nt < 4; ++nt) {
            short4v p = { f2bf(fmaxf(accS[nt][0], 0.f)),
                          f2bf(fmaxf(accS[nt][1], 0.f)),
                          f2bf(fmaxf(accS[nt][2], 0.f)),
                          f2bf(fmaxf(accS[nt][3], 0.f)) };
            *(short4v*)&HT[w][lr][nt * 16 + lg * 4] = p;
        }

        // ---- Reward layer 2 in registers ----
        float rp = 0.f;
        #pragma unroll
        for (int nt = 0; nt < 2; ++nt) {
            rp += fmaxf(accR[nt][0], 0.f) * bf2f(rw2p[nt][0]);
            rp += fmaxf(accR[nt][1], 0.f) * bf2f(rw2p[nt][1]);
            rp += fmaxf(accR[nt][2], 0.f) * bf2f(rw2p[nt][2]);
            rp += fmaxf(accR[nt][3], 0.f) * bf2f(rw2p[nt][3]);
        }
        rp += __shfl_xor(rp, 16);
        rp += __shfl_xor(rp, 32);
        if (lane < 16)
            outR[(size_t)e * Bsz + row0 + t * 64] = fminf(fmaxf(rp + rb2s, -100.f), 200.f);

        // ---- Layer 2 (state): H frags via b128 (wave-private, in-order DS) ----
        bf16x8 h0 = *(const bf16x8*)&HT[w][lr][lg * 8];
        bf16x8 h1 = *(const bf16x8*)&HT[w][lr][32 + lg * 8];
        #pragma unroll
        for (int nt = 0; nt < 4; ++nt) {
            f32x4 acc = (f32x4){ bf2f(b2p[nt][0]), bf2f(b2p[nt][1]),
                                 bf2f(b2p[nt][2]), bf2f(b2p[nt][3]) };
            acc = __builtin_amdgcn_mfma_f32_16x16x32_bf16(w2r[nt][0], h0, acc, 0, 0, 0);
            acc = __builtin_amdgcn_mfma_f32_16x16x32_bf16(w2r[nt][1], h1, acc, 0, 0, 0);
            __builtin_nontemporal_store(acc,
                (f32x4*)&outS[((size_t)e * Bsz + row0 + t * 64) * Ssz + nt * 16 + lg * 4]);
        }

        // ---- Convert prefetched f32 -> current fragments (vmcnt wait lands here) ----
        a0 = pack8(ns0, ns1);
        a1 = pack8(ns2, ns3);
        a2 = pack8(na0, na1);
    }
}

extern "C" void kernel_launch(void* const* d_in, const int* in_sizes, int n_in,
                              void* d_out, int out_size, void* d_ws, size_t ws_size,
                              hipStream_t stream) {
    const float* state  = (const float*)d_in[0];
    const float* action = (const float*)d_in[1];
    const float* W1  = (const float*)d_in[2];
    const float* b1  = (const float*)d_in[3];
    const float* W2  = (const float*)d_in[4];
    const float* b2  = (const float*)d_in[5];
    const float* rW1 = (const float*)d_in[6];
    const float* rb1 = (const float*)d_in[7];
    const float* rW2 = (const float*)d_in[8];
    const float* rb2 = (const float*)d_in[9];

    float* outS = (float*)d_out;                      // [E, B, S]
    float* outR = outS + (size_t)Esz * Bsz * Ssz;     // [E, B, 1]

    short* Wf = (short*)d_ws;                         // Esz*WELEMS bf16 fragments (426 KB)

    prep_w<<<(Esz * WELEMS) / PT, PT, 0, stream>>>(W1, rW1, W2, Wf);   // 416 blocks
    fused_all<<<Esz * (Bsz / CHUNK), NTM, 0, stream>>>(                // 512 blocks, 1 generation
        state, action, Wf, b1, b2, rb1, rW2, rb2, outS, outR);
}

// Round 14
// 28.558 us; speedup vs baseline: 1.1220x; 1.1220x over previous
//
#include <hip/hip_runtime.h>
#include <hip/hip_bf16.h>
#include <cstdint>
#include <cstddef>

// Problem constants
#define Bsz 16384
#define Esz 16
#define Ssz 64
#define Asz 32
#define Isz 96   // S + A
#define HSz 64
#define HRz 32

#define NTM 256       // 4 waves
#define CHUNK 512     // batch rows per block
#define NTILE 8       // CHUNK / (4 waves * 16 rows)

typedef __attribute__((ext_vector_type(8))) short bf16x8;
typedef __attribute__((ext_vector_type(4))) short short4v;
typedef __attribute__((ext_vector_type(4))) float f32x4;

static __device__ __forceinline__ short f2bf(float f) {
    __hip_bfloat16 b = __float2bfloat16(f);   // pairs into v_cvt_pk_bf16_f32
    return *reinterpret_cast<short*>(&b);
}
static __device__ __forceinline__ float bf2f(short s) {
    union { uint32_t u; float f; } v; v.u = ((uint32_t)(uint16_t)s) << 16; return v.f;
}
static __device__ __forceinline__ bf16x8 pack8(float4 lo, float4 hi) {
    bf16x8 r;
    r[0] = f2bf(lo.x); r[1] = f2bf(lo.y); r[2] = f2bf(lo.z); r[3] = f2bf(lo.w);
    r[4] = f2bf(hi.x); r[5] = f2bf(hi.y); r[6] = f2bf(hi.z); r[7] = f2bf(hi.w);
    return r;
}

// R12 winner + cooperative in-block weight staging (single kernel, no workspace).
// 256 threads load the block's f32 weights COALESCED (float4), convert once,
// write bf16 transposed into LDS (WT[n][k]); each lane then reads its 26 MFMA
// fragments as single ds_read_b128 (fragment = 8 consecutive k at fixed n).
// Replaces R12's per-lane 208-scalar gather duplicated across 4 waves.
// Steady-state loop, XCD swizzle, nt-stores identical to R12.
__global__ __launch_bounds__(NTM, 2)
void fused_all(const float* __restrict__ state, const float* __restrict__ action,
               const float* __restrict__ W1, const float* __restrict__ b1,
               const float* __restrict__ W2, const float* __restrict__ b2,
               const float* __restrict__ rW1, const float* __restrict__ rb1,
               const float* __restrict__ rW2, const float* __restrict__ rb2,
               float* __restrict__ outS, float* __restrict__ outR)
{
    // Transposed weight staging (row strides 104/72 shorts = 208/144 B, 16B-mult)
    __shared__ __align__(16) short WT1[HSz][104];    // 13312 B  W1^T [h][i]
    __shared__ __align__(16) short rWT1[HRz][104];   //  6656 B  rW1^T [h][i]
    __shared__ __align__(16) short WT2[Ssz][72];     //  9216 B  W2^T [s][h]
    __shared__ __align__(16) short HT[4][16][68];    //  8704 B  per-wave H transpose
    // total 37,888 B -> 2 blocks/CU fine

    // ---- XCD-aware sibling swizzle (bijective over 512 blocks) ----
    const int bid = blockIdx.x;
    const int xcd = bid & 7;
    const int rem = bid >> 3;
    const int e   = rem & (Esz - 1);
    const int c0  = (xcd + 8 * (rem >> 4)) * CHUNK;

    const int tid = threadIdx.x;
    const int w = tid >> 6, lane = tid & 63;
    const int lr = lane & 15, lg = lane >> 4;

    // ---- Cooperative staging: coalesced f32 float4 loads -> bf16 transpose in LDS ----
    {   // W1: [i][h] 6144 f32 = 1536 float4; float4 = 4 consecutive h at fixed i
        const float4* src = (const float4*)(W1 + (size_t)e * Isz * HSz);
        for (int q = tid; q < 1536; q += NTM) {
            float4 v = src[q];
            int i = q >> 4, h = (q & 15) * 4;     // q*4 = i*64 + h
            WT1[h + 0][i] = f2bf(v.x);
            WT1[h + 1][i] = f2bf(v.y);
            WT1[h + 2][i] = f2bf(v.z);
            WT1[h + 3][i] = f2bf(v.w);
        }
    }
    {   // rW1: [i][h] 3072 f32 = 768 float4; float4 = 4 consecutive h (HRz=32)
        const float4* src = (const float4*)(rW1 + (size_t)e * Isz * HRz);
        for (int q = tid; q < 768; q += NTM) {
            float4 v = src[q];
            int i = q >> 3, h = (q & 7) * 4;      // q*4 = i*32 + h
            rWT1[h + 0][i] = f2bf(v.x);
            rWT1[h + 1][i] = f2bf(v.y);
            rWT1[h + 2][i] = f2bf(v.z);
            rWT1[h + 3][i] = f2bf(v.w);
        }
    }
    {   // W2: [h][s] 4096 f32 = 1024 float4; float4 = 4 consecutive s at fixed h
        const float4* src = (const float4*)(W2 + (size_t)e * HSz * Ssz);
        for (int q = tid; q < 1024; q += NTM) {
            float4 v = src[q];
            int h = q >> 4, s = (q & 15) * 4;     // q*4 = h*64 + s
            WT2[s + 0][h] = f2bf(v.x);
            WT2[s + 1][h] = f2bf(v.y);
            WT2[s + 2][h] = f2bf(v.z);
            WT2[s + 3][h] = f2bf(v.w);
        }
    }

    // ---- Biases packed bf16 (lane's D slots: n = nt*16 + lg*4 + j) ----
    short4v b1p[4], b2p[4], rb1p[2], rw2p[2];
    #pragma unroll
    for (int nt = 0; nt < 4; ++nt) {
        float4 v1 = *(const float4*)&b1[e * HSz + nt * 16 + lg * 4];
        float4 v2 = *(const float4*)&b2[e * Ssz + nt * 16 + lg * 4];
        b1p[nt] = (short4v){ f2bf(v1.x), f2bf(v1.y), f2bf(v1.z), f2bf(v1.w) };
        b2p[nt] = (short4v){ f2bf(v2.x), f2bf(v2.y), f2bf(v2.z), f2bf(v2.w) };
    }
    #pragma unroll
    for (int nt = 0; nt < 2; ++nt) {
        float4 v1 = *(const float4*)&rb1[e * HRz + nt * 16 + lg * 4];
        float4 v2 = *(const float4*)&rW2[e * HRz + nt * 16 + lg * 4];
        rb1p[nt] = (short4v){ f2bf(v1.x), f2bf(v1.y), f2bf(v1.z), f2bf(v1.w) };
        rw2p[nt] = (short4v){ f2bf(v2.x), f2bf(v2.y), f2bf(v2.z), f2bf(v2.w) };
    }
    const float rb2s = rb2[e];

    __syncthreads();   // WT ready

    // ---- Weight fragments: one ds_read_b128 each ----
    // Fragment (nt,kk): lane holds W[k=kk*32+lg*8+t][n=nt*16+lr] = WT[n][k..k+7]
    bf16x8 w1r[4][3], rw1r[2][3], w2r[4][2];
    #pragma unroll
    for (int nt = 0; nt < 4; ++nt)
        #pragma unroll
        for (int kk = 0; kk < 3; ++kk)
            w1r[nt][kk] = *(const bf16x8*)&WT1[nt * 16 + lr][kk * 32 + lg * 8];
    #pragma unroll
    for (int nt = 0; nt < 2; ++nt)
        #pragma unroll
        for (int kk = 0; kk < 3; ++kk)
            rw1r[nt][kk] = *(const bf16x8*)&rWT1[nt * 16 + lr][kk * 32 + lg * 8];
    #pragma unroll
    for (int nt = 0; nt < 4; ++nt)
        #pragma unroll
        for (int kk = 0; kk < 2; ++kk)
            w2r[nt][kk] = *(const bf16x8*)&WT2[nt * 16 + lr][kk * 32 + lg * 8];

    // ---- X pipeline: f32 loads (prefetched) -> cvt_pk -> bf16 fragments ----
    const int row0 = c0 + w * 16 + lr;               // this lane's base batch row (m = lr)
    const float* sbase = state  + (size_t)row0 * Ssz + lg * 8;
    const float* abase = action + (size_t)row0 * Asz + lg * 8;

    float4 xs0 = *(const float4*)(sbase);
    float4 xs1 = *(const float4*)(sbase + 4);
    float4 xs2 = *(const float4*)(sbase + 32);
    float4 xs3 = *(const float4*)(sbase + 36);
    float4 xa0 = *(const float4*)(abase);
    float4 xa1 = *(const float4*)(abase + 4);
    bf16x8 a0 = pack8(xs0, xs1);
    bf16x8 a1 = pack8(xs2, xs3);
    bf16x8 a2 = pack8(xa0, xa1);

    #pragma unroll 1
    for (int t = 0; t < NTILE; ++t) {
        // Prefetch next tile's f32 rows (wraps on last iter; L2-hit, discarded)
        const int tn = (t + 1) & (NTILE - 1);
        const float* sp = sbase + (size_t)tn * 64 * Ssz;
        const float* ap = abase + (size_t)tn * 64 * Asz;
        float4 ns0 = *(const float4*)(sp);
        float4 ns1 = *(const float4*)(sp + 4);
        float4 ns2 = *(const float4*)(sp + 32);
        float4 ns3 = *(const float4*)(sp + 36);
        float4 na0 = *(const float4*)(ap);
        float4 na1 = *(const float4*)(ap + 4);

        // ---- Layer 1 (state): acc initialized with bias (free add) ----
        f32x4 accS[4];
        #pragma unroll
        for (int nt = 0; nt < 4; ++nt) {
            f32x4 acc = (f32x4){ bf2f(b1p[nt][0]), bf2f(b1p[nt][1]),
                                 bf2f(b1p[nt][2]), bf2f(b1p[nt][3]) };
            acc = __builtin_amdgcn_mfma_f32_16x16x32_bf16(w1r[nt][0], a0, acc, 0, 0, 0);
            acc = __builtin_amdgcn_mfma_f32_16x16x32_bf16(w1r[nt][1], a1, acc, 0, 0, 0);
            acc = __builtin_amdgcn_mfma_f32_16x16x32_bf16(w1r[nt][2], a2, acc, 0, 0, 0);
            accS[nt] = acc;
        }
        // ---- Layer 1 (reward) ----
        f32x4 accR[2];
        #pragma unroll
        for (int nt = 0; nt < 2; ++nt) {
            f32x4 acc = (f32x4){ bf2f(rb1p[nt][0]), bf2f(rb1p[nt][1]),
                                 bf2f(rb1p[nt][2]), bf2f(rb1p[nt][3]) };
            acc = __builtin_amdgcn_mfma_f32_16x16x32_bf16(rw1r[nt][0], a0, acc, 0, 0, 0);
            acc = __builtin_amdgcn_mfma_f32_16x16x32_bf16(rw1r[nt][1], a1, acc, 0, 0, 0);
            acc = __builtin_amdgcn_mfma_f32_16x16x32_bf16(rw1r[nt][2], a2, acc, 0, 0, 0);
            accR[nt] = acc;
        }

        // ---- H = relu(accS) -> HT (lane holds 4 consecutive h of row lr) ----
        #pragma unroll
        for (int nt = 0; nt < 4; ++nt) {
            short4v p = { f2bf(fmaxf(accS[nt][0], 0.f)),
                          f2bf(fmaxf(accS[nt][1], 0.f)),
                          f2bf(fmaxf(accS[nt][2], 0.f)),
                          f2bf(fmaxf(accS[nt][3], 0.f)) };
            *(short4v*)&HT[w][lr][nt * 16 + lg * 4] = p;
        }

        // ---- Reward layer 2 in registers ----
        float rp = 0.f;
        #pragma unroll
        for (int nt = 0; nt < 2; ++nt) {
            rp += fmaxf(accR[nt][0], 0.f) * bf2f(rw2p[nt][0]);
            rp += fmaxf(accR[nt][1], 0.f) * bf2f(rw2p[nt][1]);
            rp += fmaxf(accR[nt][2], 0.f) * bf2f(rw2p[nt][2]);
            rp += fmaxf(accR[nt][3], 0.f) * bf2f(rw2p[nt][3]);
        }
        rp += __shfl_xor(rp, 16);
        rp += __shfl_xor(rp, 32);
        if (lane < 16)
            __builtin_nontemporal_store(fminf(fmaxf(rp + rb2s, -100.f), 200.f),
                                        &outR[(size_t)e * Bsz + row0 + t * 64]);

        // ---- Layer 2 (state): H frags via b128 (wave-private, in-order DS) ----
        bf16x8 h0 = *(const bf16x8*)&HT[w][lr][lg * 8];
        bf16x8 h1 = *(const bf16x8*)&HT[w][lr][32 + lg * 8];
        #pragma unroll
        for (int nt = 0; nt < 4; ++nt) {
            f32x4 acc = (f32x4){ bf2f(b2p[nt][0]), bf2f(b2p[nt][1]),
                                 bf2f(b2p[nt][2]), bf2f(b2p[nt][3]) };
            acc = __builtin_amdgcn_mfma_f32_16x16x32_bf16(w2r[nt][0], h0, acc, 0, 0, 0);
            acc = __builtin_amdgcn_mfma_f32_16x16x32_bf16(w2r[nt][1], h1, acc, 0, 0, 0);
            __builtin_nontemporal_store(acc,
                (f32x4*)&outS[((size_t)e * Bsz + row0 + t * 64) * Ssz + nt * 16 + lg * 4]);
        }

        // ---- Convert prefetched f32 -> current fragments (vmcnt wait lands here) ----
        a0 = pack8(ns0, ns1);
        a1 = pack8(ns2, ns3);
        a2 = pack8(na0, na1);
    }
}

extern "C" void kernel_launch(void* const* d_in, const int* in_sizes, int n_in,
                              void* d_out, int out_size, void* d_ws, size_t ws_size,
                              hipStream_t stream) {
    const float* state  = (const float*)d_in[0];
    const float* action = (const float*)d_in[1];
    const float* W1  = (const float*)d_in[2];
    const float* b1  = (const float*)d_in[3];
    const float* W2  = (const float*)d_in[4];
    const float* b2  = (const float*)d_in[5];
    const float* rW1 = (const float*)d_in[6];
    const float* rb1 = (const float*)d_in[7];
    const float* rW2 = (const float*)d_in[8];
    const float* rb2 = (const float*)d_in[9];

    float* outS = (float*)d_out;                      // [E, B, S]
    float* outR = outS + (size_t)Esz * Bsz * Ssz;     // [E, B, 1]

    fused_all<<<Esz * (Bsz / CHUNK), NTM, 0, stream>>>(   // 512 blocks, 1 generation
        state, action, W1, b1, W2, b2, rW1, rb1, rW2, rb2, outS, outR);
}